// Round 4
// baseline (51.326 us; speedup 1.0000x reference)
//
#include <hip/hip_runtime.h>
#include <math.h>

#define NFR 8
#define DD 2048
#define NS 25
#define NB 64
#define NPAIR (NS*NB)          // 1600
#define NITER 32

typedef __attribute__((ext_vector_type(8))) short short8;
typedef __attribute__((ext_vector_type(4))) float f32x4;

// Branch-free acos, ~1e-7 rel (Cephes asinf core). Valid for |x| <= 1.
__device__ __forceinline__ float acos_fast(float x) {
    const float ax = fabsf(x);
    const bool big = ax > 0.5f;
    const float z = big ? 0.5f * (1.f - ax) : x * x;
    const float s = big ? sqrtf(z) : ax;
    float p = fmaf(z, 4.2163199048e-2f, 2.4181311049e-2f);
    p = fmaf(z, p, 4.5470025998e-2f);
    p = fmaf(z, p, 7.4953002686e-2f);
    p = fmaf(z, p, 1.6666752422e-1f);
    const float asin_s = fmaf(s * z, p, s);
    const float asin_abs = big ? (1.5707963267948966f - 2.f * asin_s) : asin_s;
    return 1.5707963267948966f - copysignf(asin_abs, x);
}

// Pack hi-bf16 of (a,b) and lo-bf16 remainders via v_perm_b32 (6 VALU / 2 floats).
#define SPLIT2(a, b, HI, LO) { \
    const float ha_ = __uint_as_float(__float_as_uint(a) & 0xFFFF0000u); \
    const float hb_ = __uint_as_float(__float_as_uint(b) & 0xFFFF0000u); \
    HI = __builtin_amdgcn_perm(__float_as_uint(b), __float_as_uint(a), 0x07060302u); \
    LO = __builtin_amdgcn_perm(__float_as_uint((b) - hb_), __float_as_uint((a) - ha_), 0x07060302u); \
}

// One block (4 waves) per (s,b) pair.
// Phase 1: 16x16 Gram of stacked rows [8 sup; 8 tgt] via bf16 hi/lo MFMA, split-K,
//          depth-3 software-pipelined loads (4-6 in flight per wave).
// Phase 2: lanes 0-7 solve support Frechet in 8-dim Gram coords, lanes 8-15 target.
__global__ __launch_bounds__(256) void fused_kernel(const float* __restrict__ sup,
                                                    const float* __restrict__ tgt,
                                                    float* __restrict__ out) {
    const int p   = blockIdx.x;
    const int tid = threadIdx.x;
    const int wv  = tid >> 6;
    const int l   = tid & 63;
    const int row = l & 15;
    const int kg  = l >> 4;

    __shared__ float part[4][16][17];
    __shared__ float graw[256];

    const float* rowp = (row < 8)
        ? sup + (size_t)p * (NFR*DD) + (size_t)row * DD
        : tgt + (size_t)(p & (NB-1)) * (NFR*DD) + (size_t)(row - 8) * DD;
    const float4* lp = (const float4*)rowp + (wv * 128 + kg * 2);

    // depth-3 rotating prefetch buffer (fully unrolled loop -> static indices)
    float4 fA[3], fB[3];
    fA[0] = lp[0];  fB[0] = lp[1];
    fA[1] = lp[8];  fB[1] = lp[9];
    fA[2] = lp[16]; fB[2] = lp[17];

    f32x4 accA = {0.f, 0.f, 0.f, 0.f};
    f32x4 accB = {0.f, 0.f, 0.f, 0.f};
    #pragma unroll
    for (int c = 0; c < 16; ++c) {
        const int s = c % 3;
        const float4 f0 = fA[s];
        const float4 f1 = fB[s];
        if (c + 3 < 16) {
            fA[s] = lp[(c + 3) * 8];
            fB[s] = lp[(c + 3) * 8 + 1];
        }
        union { unsigned int u[4]; short8 s8; } H, L;
        SPLIT2(f0.x, f0.y, H.u[0], L.u[0]);
        SPLIT2(f0.z, f0.w, H.u[1], L.u[1]);
        SPLIT2(f1.x, f1.y, H.u[2], L.u[2]);
        SPLIT2(f1.z, f1.w, H.u[3], L.u[3]);
        accA = __builtin_amdgcn_mfma_f32_16x16x32_bf16(H.s8, H.s8, accA, 0, 0, 0);
        accB = __builtin_amdgcn_mfma_f32_16x16x32_bf16(H.s8, L.s8, accB, 0, 0, 0);
        accB = __builtin_amdgcn_mfma_f32_16x16x32_bf16(L.s8, H.s8, accB, 0, 0, 0);
    }
    #pragma unroll
    for (int r = 0; r < 4; ++r)
        part[wv][kg * 4 + r][row] = accA[r] + accB[r];
    __syncthreads();

    {
        const int rr = tid >> 4, cc = tid & 15;
        graw[rr * 16 + cc] = part[0][rr][cc] + part[1][rr][cc]
                           + part[2][rr][cc] + part[3][rr][cc];
    }
    __syncthreads();

    if (tid < 16) {
        const int j = tid & 7;
        const int base = tid & 8;              // 0 for sup half, 8 for tgt half
        const int R = base + j;
        const int cb = base;

        const float invn_own = rsqrtf(fmaxf(graw[R * 16 + R], 1e-14f));
        float Grow[8];
        #pragma unroll
        for (int k = 0; k < 8; ++k) {
            const float invk = rsqrtf(fmaxf(graw[(cb + k) * 16 + (cb + k)], 1e-14f));
            Grow[k] = graw[R * 16 + cb + k] * invn_own * invk;
        }

        // mu0 = normalize(mean X^): a_k = rsqrt(sum G)
        float rs = 0.f;
        #pragma unroll
        for (int k = 0; k < 8; ++k) rs += Grow[k];
        rs += __shfl_xor(rs, 1, 8);
        rs += __shfl_xor(rs, 2, 8);
        rs += __shfl_xor(rs, 4, 8);
        float a_own = rsqrtf(fmaxf(rs, 6.4e-13f));
        float aAll[8];
        #pragma unroll
        for (int k = 0; k < 8; ++k) aAll[k] = a_own;

        for (int it = 0; it < NITER; ++it) {
            float dot = 0.f;
            #pragma unroll
            for (int k = 0; k < 8; ++k) dot = fmaf(Grow[k], aAll[k], dot);
            dot = fminf(fmaxf(dot, -1.f + 1e-6f), 1.f - 1e-6f);
            const float theta = acos_fast(dot);
            const float q = fmaf(-dot, dot, 1.0f);          // sin^2(theta)
            const float coef = (theta > 1e-4f) ? theta * rsqrtf(q) : 1.f;
            const float w = 0.125f * coef;
            float wAll[8];
            #pragma unroll
            for (int k = 0; k < 8; ++k) wAll[k] = __shfl(w, base + k, 16);
            float Gw = 0.f;
            #pragma unroll
            for (int k = 0; k < 8; ++k) Gw = fmaf(Grow[k], wAll[k], Gw);
            // two interleaved 8-lane reductions: cdavg = a^T G w, wGw = w^T G w
            float u1 = a_own * Gw, u2 = w * Gw;
            u1 += __shfl_xor(u1, 1, 8);  u2 += __shfl_xor(u2, 1, 8);
            u1 += __shfl_xor(u1, 2, 8);  u2 += __shfl_xor(u2, 2, 8);
            u1 += __shfl_xor(u1, 4, 8);  u2 += __shfl_xor(u2, 4, 8);
            const float cdavg = u1;
            const float vnsq = fmaxf(u2 - cdavg * cdavg, 0.f);   // ||v||^2
            const float vn = sqrtf(vnsq);
            const float rev = vn * 0.15915494309189535f;
            const float sinv = __builtin_amdgcn_sinf(rev);       // sin(vn)
            const float cosv = __builtin_amdgcn_cosf(rev);       // cos(vn)
            const float sinc = (vn > 1e-9f) ? sinv / vn : 1.f;
            // ||mu_new||^2 = cos^2 + sinc^2 * ||v||^2  (a^T G b = 0 algebraically)
            const float cn2 = fmaf(sinc * sinc, vnsq, cosv * cosv);
            const float rn = rsqrtf(fmaxf(cn2, 1e-14f));
            a_own = (cosv * a_own + sinc * fmaf(-cdavg, a_own, w)) * rn;
            #pragma unroll
            for (int k = 0; k < 8; ++k)
                aAll[k] = (cosv * aAll[k] + sinc * fmaf(-cdavg, aAll[k], wAll[k])) * rn;
        }

        // sim = sum_{j,l} ahat_sup_j * Craw[j][l] * ahat_tgt_l
        const float ahat = a_own * invn_own;
        float at[8];
        #pragma unroll
        for (int q2 = 0; q2 < 8; ++q2) at[q2] = __shfl(ahat, 8 + q2, 16);
        float tacc = 0.f;
        #pragma unroll
        for (int q2 = 0; q2 < 8; ++q2) tacc = fmaf(graw[j * 16 + 8 + q2], at[q2], tacc);
        float sim = ahat * tacc;
        sim += __shfl_xor(sim, 1, 8);
        sim += __shfl_xor(sim, 2, 8);
        sim += __shfl_xor(sim, 4, 8);
        if (tid == 0) out[p] = sim;
    }
}

extern "C" void kernel_launch(void* const* d_in, const int* in_sizes, int n_in,
                              void* d_out, int out_size, void* d_ws, size_t ws_size,
                              hipStream_t stream) {
    const float* sup = (const float*)d_in[0];   // [25,64,8,2048] f32
    const float* tgt = (const float*)d_in[1];   // [64,8,2048] f32
    float* out = (float*)d_out;                 // [25,64] f32
    fused_kernel<<<NPAIR, 256, 0, stream>>>(sup, tgt, out);
}